// Round 27
// baseline (675.864 us; speedup 1.0000x reference)
//
#include <hip/hip_runtime.h>
#include <hip/hip_bf16.h>
#include <math.h>

// SNN forward: 64 -> 1024 -> 1024 -> 10, T=4000, B=16, LIF beta=exp(-0.025),
// thr=1, hard reset to 0, Dale clamp W>=0.
// R27: R26's scan_hidden v2 with the buffer-aliasing WAR race FIXED:
// prefetch-before-process at depth 3 requires FOUR segment buffers
// ((s+3)%3 == s%3 aliased; %4 does not). Waits unchanged (re-derived):
// prologue 20/25/30, steady 35, tail 25/15. Everything else = R25 (658us):
// gemm8 shared-A, scan_out/scan_l0 tails, merged prep, bit-packed output.

#define T_STEPS 4000
#define NB 16
#define N_IN 64
#define NH 1024
#define N_OUT 10
#define SEGO 40
#define SEGH 40

typedef __attribute__((ext_vector_type(8))) short bf16x8;
typedef __attribute__((ext_vector_type(8))) unsigned short u16x8;
typedef __attribute__((ext_vector_type(4))) float f32x4;
typedef __hip_bfloat16 bf16;
typedef unsigned long long u64;

#define ASG(p) (const __attribute__((address_space(1))) void*)(p)
#define ASL(p) (__attribute__((address_space(3))) void*)(p)

#define BETA_C 0.97530991202833261687f   // float(exp(-0.025))

// ---------------- merged prep kernel ----------------

__global__ __launch_bounds__(256) void k_prep(
    const float* __restrict__ in_sp, u64* __restrict__ mask,
    const float* __restrict__ W1, bf16* __restrict__ BT1,
    const float* __restrict__ W2, bf16* __restrict__ BT2,
    float* __restrict__ mst, int nM, int ZB, int MB) {
    __shared__ float Wlds[64][65];
    int b = blockIdx.x;
    const int tid = threadIdx.x;
    if (b < ZB) {                                  // zero membrane states
        int i = b * 256 + tid;
        if (i < nM) mst[i] = 0.f;
        return;
    }
    b -= ZB;
    if (b < MB) {                                  // input spike masks
        int w = b * 4 + (tid >> 6);
        int lane = tid & 63;
        float v = in_sp[(size_t)w * 64 + lane];
        u64 bal = __ballot(v > 0.5f);
        if (lane == 0) mask[w] = bal;
        return;
    }
    b -= MB;
    if (b < 256) {                                 // limbs_t: BT1 interleaved
        const int lane = tid & 63;
        const int wr   = tid >> 6;
        const int k0 = (b & 15) * 64;
        const int n0 = (b >> 4) * 64;
#pragma unroll
        for (int rr = 0; rr < 16; ++rr) {
            int kl = wr * 16 + rr;
            Wlds[kl][lane] = W1[(size_t)(k0 + kl) * 1024 + n0 + lane];
        }
        __syncthreads();
#pragma unroll
        for (int rr = 0; rr < 16; ++rr) {
            int nl = wr * 16 + rr;
            float w = fmaxf(Wlds[lane][nl], 0.f);  // Dale's law clamp
            bf16 h = __float2bfloat16(w);
            float hf = __bfloat162float(h);
            bf16 l = __float2bfloat16(w - hf);
            size_t base = (size_t)(n0 + nl) * 2048 + 2 * k0 + lane;
            BT1[base] = h;
            BT1[base + 64] = l;
        }
        return;
    }
    b -= 256;
    {                                              // limbs: BT2 [128][2048]
        int idx = b * 256 + tid;
        int total = 128 * 2 * NH;
        if (idx >= total) return;
        int n  = idx / (2 * NH);
        int k2 = idx - n * (2 * NH);
        int lo = (k2 >= NH);
        int k = lo ? (k2 - NH) : k2;
        float v = 0.f;
        if (n < N_OUT) {
            float w = fmaxf(W2[(size_t)k * N_OUT + n], 0.f);
            float hi = __bfloat162float(__float2bfloat16(w));
            v = lo ? (w - hi) : w;
        }
        BT2[idx] = __float2bfloat16(v);
    }
}

// Unpack scan_out bit-spikes.
__global__ void k_unpack(const u64* __restrict__ BITS, float* __restrict__ out,
                         int total) {
    int idx = blockIdx.x * 256 + threadIdx.x;
    if (idx >= total) return;
    int t   = idx / (NB * N_OUT);
    int rem = idx - t * (NB * N_OUT);
    int b = rem / N_OUT;
    int k = rem - b * N_OUT;
    u64 w = BITS[(size_t)(t / SEGO) * 256 + b * 16 + k];
    out[idx] = ((w >> (t % SEGO)) & 1ULL) ? 1.f : 0.f;
}

// ---------------- scan_out body (standalone + gemm8 tail) ----------------

__device__ __forceinline__ void scan_out_body(
    const float* __restrict__ I2, const float* __restrict__ bias,
    float* __restrict__ mstate, u64* __restrict__ BITS,
    int Tc, float* seg, int tid) {
    float* segA = seg;
    float* segB = seg + SEGO * 256;
    const bool act = tid < 256;
    const int lane = tid & 63;
    const int wave = tid >> 6;
    const int k = tid & 15;
    float m = 0.f, bj = 0.f;
    if (act) {
        m = mstate[tid];
        bj = (k < N_OUT) ? bias[k] : 0.f;
    }
    const int nseg = Tc / SEGO;                  // even

#define O_PREFETCH(SEGBUF, SIDX)                                            \
    if (act) {                                                              \
        const float* src = I2 + (size_t)(SIDX) * SEGO * 256                 \
                              + (size_t)wave * 256 + lane * 4;              \
        _Pragma("unroll")                                                   \
        for (int g = 0; g < SEGO / 4; ++g)                                  \
            __builtin_amdgcn_global_load_lds(                               \
                ASG(src + (size_t)(g * 4) * 256),                           \
                ASL(&SEGBUF[(g * 4 + wave) * 256]), 16, 0, 0);              \
    }

#define O_PROC(SEGBUF, SIDX)                                                \
    if (act) {                                                              \
        u64 obits = 0;                                                      \
        _Pragma("unroll")                                                   \
        for (int sb = 0; sb < SEGO / 8; ++sb) {                             \
            float v[8];                                                     \
            _Pragma("unroll")                                               \
            for (int u = 0; u < 8; ++u)                                     \
                v[u] = SEGBUF[(sb * 8 + u) * 256 + tid];                    \
            _Pragma("unroll")                                               \
            for (int u = 0; u < 8; ++u) {                                   \
                m = fmaf(BETA_C, m, v[u] + bj);                             \
                bool sp = (m >= 1.0f);                                      \
                obits |= ((u64)(sp ? 1 : 0)) << (sb * 8 + u);               \
                m = sp ? 0.f : m;                                           \
            }                                                               \
        }                                                                   \
        BITS[(size_t)(SIDX) * 256 + tid] = obits;                           \
    }

    O_PREFETCH(segA, 0);
    O_PREFETCH(segB, 1);
    asm volatile("s_waitcnt vmcnt(10)" ::: "memory");
    __builtin_amdgcn_sched_barrier(0);
    __builtin_amdgcn_s_barrier();
    for (int s = 0; s < nseg; s += 2) {
        O_PROC(segA, s);
        if (s + 2 < nseg) {
            O_PREFETCH(segA, s + 2);
            asm volatile("s_waitcnt vmcnt(11)" ::: "memory");
        } else {
            asm volatile("s_waitcnt vmcnt(1)" ::: "memory");
        }
        __builtin_amdgcn_sched_barrier(0);
        __builtin_amdgcn_s_barrier();
        O_PROC(segB, s + 1);
        if (s + 3 < nseg) {
            O_PREFETCH(segB, s + 3);
            asm volatile("s_waitcnt vmcnt(11)" ::: "memory");
            __builtin_amdgcn_sched_barrier(0);
            __builtin_amdgcn_s_barrier();
        } else if (s + 2 < nseg) {
            asm volatile("s_waitcnt vmcnt(1)" ::: "memory");
            __builtin_amdgcn_sched_barrier(0);
            __builtin_amdgcn_s_barrier();
        }
    }
    if (act) mstate[tid] = m;
#undef O_PREFETCH
#undef O_PROC
}

__global__ __launch_bounds__(256) void k_scan_out(
    const float* __restrict__ I2, const float* __restrict__ bias,
    float* __restrict__ mstate, u64* __restrict__ BITS, int Tc) {
    __shared__ __align__(16) float seg[2 * SEGO * 256];
    scan_out_body(I2, bias, mstate, BITS, Tc, seg, threadIdx.x);
}

// ---------------- scan_l0 body (standalone + gemm8 tail) ----------------

__device__ __forceinline__ void scan_l0_body(
    const u64* __restrict__ mask, const float* __restrict__ W0,
    const float* __restrict__ bias, float* __restrict__ mstate,
    bf16* __restrict__ S, int Tc, int b0, int lane, float* IL) {
    const int b  = b0 >> 4;
    const int q  = b0 & 15;
    const int j0 = q * 64;
    const int gid = b0 * 64 + lane;
    const int r16 = lane & 15;
    const int kg  = lane >> 4;
    bf16x8 bh[4][2], bl[4][2];
#pragma unroll
    for (int jt = 0; jt < 4; ++jt)
#pragma unroll
        for (int kk = 0; kk < 2; ++kk)
#pragma unroll
            for (int e = 0; e < 8; ++e) {
                int k = kk * 32 + kg * 8 + e;
                float w = fmaxf(W0[(size_t)k * 1024 + j0 + jt * 16 + r16], 0.f);
                bf16 h = __float2bfloat16(w);
                float hf = __bfloat162float(h);
                bf16 l = __float2bfloat16(w - hf);
                bh[jt][kk][e] = *(short*)&h;
                bl[jt][kk][e] = *(short*)&l;
            }
    float m = mstate[gid];
    const float bj = bias[j0 + lane];
    const size_t stride = (size_t)NB * NH;
    const int ntile = Tc / 16;
    const int tmax = ntile - 1;

#define LOADM(TT) mask[(size_t)(((TT) <= tmax ? (TT) : tmax) * 16 + r16) * NB + b]

#define L0_COMPUTE(MSK, P)                                                  \
    {                                                                       \
        f32x4 acc[4] = {};                                                  \
        _Pragma("unroll")                                                   \
        for (int kk = 0; kk < 2; ++kk) {                                    \
            unsigned byte8 = (unsigned)(((MSK) >> (kk * 32 + kg * 8)) & 0xFF); \
            bf16x8 af;                                                      \
            _Pragma("unroll")                                               \
            for (int e = 0; e < 8; ++e)                                     \
                af[e] = ((byte8 >> e) & 1) ? (short)0x3F80 : (short)0;      \
            _Pragma("unroll")                                               \
            for (int jt = 0; jt < 4; ++jt) {                                \
                acc[jt] = __builtin_amdgcn_mfma_f32_16x16x32_bf16(          \
                    af, bh[jt][kk], acc[jt], 0, 0, 0);                      \
                acc[jt] = __builtin_amdgcn_mfma_f32_16x16x32_bf16(          \
                    af, bl[jt][kk], acc[jt], 0, 0, 0);                      \
            }                                                               \
        }                                                                   \
        _Pragma("unroll")                                                   \
        for (int jt = 0; jt < 4; ++jt)                                      \
            _Pragma("unroll")                                               \
            for (int rr = 0; rr < 4; ++rr)                                  \
                IL[(P) * 1088 + (kg * 4 + rr) * 68 + jt * 16 + r16] = acc[jt][rr]; \
    }

    u64 mc = LOADM(0);
    L0_COMPUTE(mc, 0);
    u64 mn = LOADM(1);
    for (int tt = 0; tt < ntile; ++tt) {
        __builtin_amdgcn_s_barrier();            // tile tt resident
        float v[16];
#pragma unroll
        for (int u = 0; u < 16; ++u)
            v[u] = IL[(tt & 1) * 1088 + u * 68 + lane];
        u64 m2 = LOADM(tt + 2);
        if (tt + 1 < ntile) L0_COMPUTE(mn, (tt + 1) & 1);
        unsigned short o[16];
#pragma unroll
        for (int u = 0; u < 16; ++u) {
            m = fmaf(BETA_C, m, v[u] + bj);
            bool sp = (m >= 1.0f);
            o[u] = sp ? (unsigned short)0x3F80 : (unsigned short)0;
            m = sp ? 0.f : m;
        }
#pragma unroll
        for (int u = 0; u < 16; ++u)
            ((unsigned short*)S)[(size_t)(tt * 16 + u) * stride + gid] = o[u];
        mn = m2;
    }
    mstate[gid] = m;
#undef L0_COMPUTE
#undef LOADM
}

__global__ __launch_bounds__(64) void k_scan_l0(
    const u64* __restrict__ mask, const float* __restrict__ W0,
    const float* __restrict__ bias, float* __restrict__ mstate,
    bf16* __restrict__ S, int Tc) {
    __shared__ __align__(16) float IL[2 * 16 * 68];
    scan_l0_body(mask, W0, bias, mstate, S, Tc, blockIdx.x, threadIdx.x, IL);
}

// ---------------- thin GEMM v2 (layer 2) ----------------

__global__ __launch_bounds__(256) void k_gemm_thin(
    const bf16* __restrict__ A, const bf16* __restrict__ BT,
    float* __restrict__ C) {
    const int tid  = threadIdx.x;
    const int lane = tid & 63;
    const int wave = tid >> 6;
    const int r16 = lane & 15;
    const int kg  = lane >> 4;
    const int m0 = blockIdx.x * 64 + wave * 16;
    f32x4 acc = {};
    const bf16* ap = A + (size_t)(m0 + r16) * 1024 + kg * 8;
    const bf16* bh = BT + (size_t)r16 * 2048 + kg * 8;
    const bf16* bl = bh + 1024;
#pragma unroll 8
    for (int kt = 0; kt < 32; ++kt) {
        const int ka = kt * 32;
        bf16x8 af  = *(const bf16x8*)(ap + ka);
        bf16x8 bfh = *(const bf16x8*)(bh + ka);
        bf16x8 bfl = *(const bf16x8*)(bl + ka);
        acc = __builtin_amdgcn_mfma_f32_16x16x32_bf16(af, bfh, acc, 0, 0, 0);
        acc = __builtin_amdgcn_mfma_f32_16x16x32_bf16(af, bfl, acc, 0, 0, 0);
    }
#pragma unroll
    for (int rr = 0; rr < 4; ++rr)
        C[(size_t)(m0 + kg * 4 + rr) * 16 + r16] = acc[rr];
}

// ---------------- 256^2 8-phase GEMM (layer 1), shared-A iteration ---------

__global__ __launch_bounds__(512) void k_gemm8(
    const bf16* __restrict__ A, const bf16* __restrict__ BT,
    float* __restrict__ C, int gx,
    const float* __restrict__ I2t, const float* __restrict__ b2t,
    float* __restrict__ m2t, u64* __restrict__ BITSt, int tcT, int doTailOut,
    const u64* __restrict__ maskN, const float* __restrict__ W0N,
    const float* __restrict__ b0N, float* __restrict__ m0N,
    bf16* __restrict__ SN, int nL0blk) {
    __shared__ __align__(16) char LDS[131072];
    const int tid  = threadIdx.x;
    const int lane = tid & 63;
    const int wave = tid >> 6;

    const int nwg = gridDim.x - doTailOut - nL0blk;
    const int wg  = blockIdx.x;
    if (wg >= nwg) {
        int tix = wg - nwg;
        if (tix < doTailOut) {
            scan_out_body(I2t, b2t, m2t, BITSt, tcT, (float*)LDS, tid);
        } else {
            int unit = (tix - doTailOut) * 8 + wave;
            float* IL = (float*)LDS + wave * 2176;
            scan_l0_body(maskN, W0N, b0N, m0N, SN, tcT, unit, lane, IL);
        }
        return;
    }

    const int KA = 1024;
    const int q = nwg >> 3, r = nwg & 7;
    const int xcd = wg & 7, idx0 = wg >> 3;
    const int swz = (xcd < r ? xcd * (q + 1) : r * (q + 1) + (xcd - r) * q) + idx0;
    const int gy = nwg / gx;              // 4
    const int n0 = (swz % gy) * 256;
    const int m0 = (swz / gy) * 256;

    const int wm = (wave >> 2) * 128;
    const int wn = (wave & 3) * 64;
    const int r16l = lane & 15;
    const int kg   = lane >> 4;
    const int hA   = wave >> 2;
    const int hB   = (wave & 3) >> 1;
    const int wn64 = wave & 1;

    const int po = (r16l * 64 + kg * 16) ^ (((r16l >> 3) & 1) << 5);
    const char* bA[2] = { LDS + hA * 16384 + po,
                          LDS + 32768 + hA * 16384 + po };
    const char* bB[2] = { LDS + 65536 + hB * 16384 + po,
                          LDS + 98304 + hB * 16384 + po };
    const int bOff = wn64 * 8192;

    int s_row[2], s_col[2];
#pragma unroll
    for (int rr = 0; rr < 2; ++rr) {
        int d = (rr * 512 + tid) * 16;
        int l = d ^ (((d >> 9) & 1) << 5);
        int sub = l >> 10;
        int w = l & 1023;
        s_row[rr] = (sub >> 1) * 16 + (w >> 6);
        s_col[rr] = ((sub & 1) * 64 + (w & 63)) >> 1;
    }

#define STAGE_A(ADST, HALF, K0)                                             \
    {                                                                       \
        _Pragma("unroll")                                                   \
        for (int rr = 0; rr < 2; ++rr)                                      \
            __builtin_amdgcn_global_load_lds(                               \
                ASG(A + (size_t)(m0 + (HALF) * 128 + s_row[rr]) * KA        \
                    + (K0) + s_col[rr]),                                    \
                ASL(LDS + (ADST) * 32768 + (HALF) * 16384                   \
                    + (rr * 512 + wave * 64) * 16),                         \
                16, 0, 0);                                                  \
    }
#define STAGE_B(BUF, HALF, K0)                                              \
    {                                                                       \
        _Pragma("unroll")                                                   \
        for (int rr = 0; rr < 2; ++rr)                                      \
            __builtin_amdgcn_global_load_lds(                               \
                ASG(BT + (size_t)(n0 + (HALF) * 128 + s_row[rr]) * 2048     \
                    + (K0) + s_col[rr]),                                    \
                ASL(LDS + 65536 + (BUF) * 32768 + (HALF) * 16384            \
                    + (rr * 512 + wave * 64) * 16),                         \
                16, 0, 0);                                                  \
    }

    f32x4 acc[8][4] = {};
    bf16x8 a[4][2], b[4][2];

#define MM(MIB, NIB)                                                        \
    {                                                                       \
        _Pragma("unroll")                                                   \
        for (int i = 0; i < 4; ++i)                                         \
            _Pragma("unroll")                                               \
            for (int j = 0; j < 2; ++j) {                                   \
                acc[(MIB) + i][(NIB) + j] =                                 \
                    __builtin_amdgcn_mfma_f32_16x16x32_bf16(                \
                        a[i][0], b[(NIB) + j][0], acc[(MIB) + i][(NIB) + j], 0, 0, 0); \
                acc[(MIB) + i][(NIB) + j] =                                 \
                    __builtin_amdgcn_mfma_f32_16x16x32_bf16(                \
                        a[i][1], b[(NIB) + j][1], acc[(MIB) + i][(NIB) + j], 0, 0, 0); \
            }                                                               \
    }

#define PH_SYNC()                                                           \
    __builtin_amdgcn_s_barrier();                                           \
    asm volatile("s_waitcnt lgkmcnt(0)" ::: "memory");                      \
    __builtin_amdgcn_sched_barrier(0);

#define KT_EVEN(ABUF, BKN, AKN)                                             \
    {                                                                       \
        _Pragma("unroll")                                                   \
        for (int i = 0; i < 4; ++i) {                                       \
            a[i][0] = *(const bf16x8*)(bA[ABUF] + i * 2048);                \
            a[i][1] = *(const bf16x8*)(bA[ABUF] + i * 2048 + 1024);         \
        }                                                                   \
        _Pragma("unroll")                                                   \
        for (int j = 0; j < 2; ++j) {                                       \
            b[j][0] = *(const bf16x8*)(bB[0] + bOff + j * 2048);            \
            b[j][1] = *(const bf16x8*)(bB[0] + bOff + j * 2048 + 1024);     \
        }                                                                   \
        PH_SYNC();                                                          \
        __builtin_amdgcn_s_setprio(1);                                      \
        MM(0, 0);                                                           \
        __builtin_amdgcn_s_setprio(0);                                      \
        __builtin_amdgcn_s_barrier();                                       \
        _Pragma("unroll")                                                   \
        for (int j = 0; j < 2; ++j) {                                       \
            b[2 + j][0] = *(const bf16x8*)(bB[0] + bOff + (2 + j) * 2048);  \
            b[2 + j][1] = *(const bf16x8*)(bB[0] + bOff + (2 + j) * 2048 + 1024); \
        }                                                                   \
        PH_SYNC();                                                          \
        __builtin_amdgcn_s_setprio(1);                                      \
        MM(0, 2);                                                           \
        __builtin_amdgcn_s_setprio(0);                                      \
        __builtin_amdgcn_s_barrier();                                       \
        _Pragma("unroll")                                                   \
        for (int i = 0; i < 4; ++i) {                                       \
            a[i][0] = *(const bf16x8*)(bA[ABUF] + (4 + i) * 2048);          \
            a[i][1] = *(const bf16x8*)(bA[ABUF] + (4 + i) * 2048 + 1024);   \
        }                                                                   \
        STAGE_B(0, 0, BKN);                                                 \
        STAGE_B(0, 1, BKN);                                                 \
        PH_SYNC();                                                          \
        __builtin_amdgcn_s_setprio(1);                                      \
        MM(4, 0);                                                           \
        __builtin_amdgcn_s_setprio(0);                                      \
        __builtin_amdgcn_s_barrier();                                       \
        STAGE_A((ABUF) ^ 1, 0, AKN);                                        \
        STAGE_A((ABUF) ^ 1, 1, AKN);                                        \
        PH_SYNC();                                                          \
        __builtin_amdgcn_s_setprio(1);                                      \
        MM(4, 2);                                                           \
        __builtin_amdgcn_s_setprio(0);                                      \
        asm volatile("s_waitcnt vmcnt(8)" ::: "memory");                    \
        __builtin_amdgcn_sched_barrier(0);                                  \
        __builtin_amdgcn_s_barrier();                                       \
    }

#define KT_ODD(ABUF, BKN)                                                   \
    {                                                                       \
        _Pragma("unroll")                                                   \
        for (int i = 0; i < 4; ++i) {                                       \
            a[i][0] = *(const bf16x8*)(bA[ABUF] + i * 2048);                \
            a[i][1] = *(const bf16x8*)(bA[ABUF] + i * 2048 + 1024);         \
        }                                                                   \
        _Pragma("unroll")                                                   \
        for (int j = 0; j < 2; ++j) {                                       \
            b[j][0] = *(const bf16x8*)(bB[1] + bOff + j * 2048);            \
            b[j][1] = *(const bf16x8*)(bB[1] + bOff + j * 2048 + 1024);     \
        }                                                                   \
        PH_SYNC();                                                          \
        __builtin_amdgcn_s_setprio(1);                                      \
        MM(0, 0);                                                           \
        __builtin_amdgcn_s_setprio(0);                                      \
        __builtin_amdgcn_s_barrier();                                       \
        _Pragma("unroll")                                                   \
        for (int j = 0; j < 2; ++j) {                                       \
            b[2 + j][0] = *(const bf16x8*)(bB[1] + bOff + (2 + j) * 2048);  \
            b[2 + j][1] = *(const bf16x8*)(bB[1] + bOff + (2 + j) * 2048 + 1024); \
        }                                                                   \
        PH_SYNC();                                                          \
        __builtin_amdgcn_s_setprio(1);                                      \
        MM(0, 2);                                                           \
        __builtin_amdgcn_s_setprio(0);                                      \
        __builtin_amdgcn_s_barrier();                                       \
        _Pragma("unroll")                                                   \
        for (int i = 0; i < 4; ++i) {                                       \
            a[i][0] = *(const bf16x8*)(bA[ABUF] + (4 + i) * 2048);          \
            a[i][1] = *(const bf16x8*)(bA[ABUF] + (4 + i) * 2048 + 1024);   \
        }                                                                   \
        STAGE_B(1, 0, BKN);                                                 \
        STAGE_B(1, 1, BKN);                                                 \
        PH_SYNC();                                                          \
        __builtin_amdgcn_s_setprio(1);                                      \
        MM(4, 0);                                                           \
        __builtin_amdgcn_s_setprio(0);                                      \
        __builtin_amdgcn_s_barrier();                                       \
        PH_SYNC();                                                          \
        __builtin_amdgcn_s_setprio(1);                                      \
        MM(4, 2);                                                           \
        __builtin_amdgcn_s_setprio(0);                                      \
        asm volatile("s_waitcnt vmcnt(4)" ::: "memory");                    \
        __builtin_amdgcn_sched_barrier(0);                                  \
        __builtin_amdgcn_s_barrier();                                       \
    }

    STAGE_B(0, 0, 0);  STAGE_B(0, 1, 0);
    STAGE_A(0, 0, 0);  STAGE_A(0, 1, 0);
    STAGE_B(1, 0, 64); STAGE_B(1, 1, 64);
    asm volatile("s_waitcnt vmcnt(4)" ::: "memory");
    __builtin_amdgcn_sched_barrier(0);
    __builtin_amdgcn_s_barrier();

    for (int it2 = 0; it2 < 16; it2 += 2) {
        const int ak1 = (64 * (it2 + 1)) & 1023;
        const int be1 = (128 * (it2 + 1)) & 2047;
        KT_EVEN(0, be1, ak1);
        KT_ODD(0, be1 + 64);
        const int ak2 = (64 * (it2 + 2)) & 1023;
        const int be2 = (128 * (it2 + 2)) & 2047;
        KT_EVEN(1, be2, ak2);
        KT_ODD(1, be2 + 64);
    }
    asm volatile("s_waitcnt vmcnt(0)" ::: "memory");
    __builtin_amdgcn_sched_barrier(0);

#pragma unroll
    for (int mi = 0; mi < 8; ++mi)
#pragma unroll
        for (int ni = 0; ni < 4; ++ni)
#pragma unroll
            for (int rr = 0; rr < 4; ++rr) {
                int row = m0 + wm + mi * 16 + kg * 4 + rr;
                int col = n0 + wn + ni * 16 + r16l;
                C[(size_t)row * 1024 + col] = acc[mi][ni][rr];
            }
#undef KT_ODD
#undef KT_EVEN
#undef PH_SYNC
#undef MM
#undef STAGE_A
#undef STAGE_B
}

// ---------------- hidden layer 1 scan v3 (R27) ----------------
// 3-deep prefetch with FOUR segment buffers (s%4 -- no aliasing with
// prefetch-before-process) + LDS-assembled 16B stores (5/segment).
// Waits: prologue 20/25/30, steady 35, tail 25/15. Requires nseg >= 6.

__global__ __launch_bounds__(64) void k_scan_hidden(
    const float* __restrict__ I, const float* __restrict__ bias,
    float* __restrict__ mstate, bf16* __restrict__ S, int Tc, float beta) {
    __shared__ __align__(16) float seg4[4 * SEGH * 64];
    __shared__ __align__(16) unsigned short OST[SEGH * 64];
    const int lane = threadIdx.x;
    const int gid  = blockIdx.x * 64 + lane;
    const int j = gid & (NH - 1);
    float m = mstate[gid];
    const float bj = bias[j];
    const size_t stride = (size_t)NB * NH;
    const int nseg = Tc / SEGH;                  // 50 / 20 / 10
    const int lrow = lane >> 4;
    const int lcol = (lane & 15) << 2;
    unsigned short* Sp = (unsigned short*)S + blockIdx.x * 64;

#define H_PRE(SIDX)                                                         \
    {                                                                       \
        const float* src = I + (size_t)(SIDX) * SEGH * stride               \
                             + (size_t)lrow * stride + blockIdx.x * 64 + lcol; \
        float* dst = seg4 + ((SIDX) & 3) * (SEGH * 64);                     \
        _Pragma("unroll")                                                   \
        for (int g = 0; g < SEGH / 4; ++g)                                  \
            __builtin_amdgcn_global_load_lds(                               \
                ASG(src + (size_t)(g * 4) * stride),                        \
                ASL(dst + g * 256), 16, 0, 0);                              \
    }

#define H_PROC(SIDX)                                                        \
    {                                                                       \
        const float* sb = seg4 + ((SIDX) & 3) * (SEGH * 64);                \
        const int btt = (SIDX) * SEGH;                                      \
        _Pragma("unroll")                                                   \
        for (int q8 = 0; q8 < SEGH / 8; ++q8) {                             \
            float v[8];                                                     \
            _Pragma("unroll")                                               \
            for (int u = 0; u < 8; ++u)                                     \
                v[u] = sb[(q8 * 8 + u) * 64 + lane];                        \
            _Pragma("unroll")                                               \
            for (int u = 0; u < 8; ++u) {                                   \
                m = fmaf(beta, m, v[u] + bj);                               \
                bool sp = (m >= 1.0f);                                      \
                OST[(q8 * 8 + u) * 64 + lane] =                             \
                    sp ? (unsigned short)0x3F80 : (unsigned short)0;        \
                m = sp ? 0.f : m;                                           \
            }                                                               \
        }                                                                   \
        asm volatile("s_waitcnt lgkmcnt(0)" ::: "memory");                  \
        __builtin_amdgcn_sched_barrier(0);                                  \
        _Pragma("unroll")                                                   \
        for (int g = 0; g < SEGH / 8; ++g) {                                \
            int rrow = g * 8 + (lane >> 3);                                 \
            u16x8 val = *(const u16x8*)&OST[rrow * 64 + (lane & 7) * 8];    \
            *(u16x8*)&Sp[(size_t)(btt + rrow) * stride + (lane & 7) * 8] = val; \
        }                                                                   \
    }

#define HW(N) asm volatile("s_waitcnt vmcnt(" #N ")" ::: "memory");         \
              __builtin_amdgcn_sched_barrier(0);

    // prologue: 3 segments in flight
    H_PRE(0); H_PRE(1); H_PRE(2);
    HW(20); H_PRE(3); H_PROC(0);
    HW(25); H_PRE(4); H_PROC(1);
    HW(30); H_PRE(5); H_PROC(2);
    // steady: wait(35) -> prefetch(s+3) -> process(s)
    for (int s = 3; s < nseg - 2; ++s) {
        HW(35);
        if (s + 3 < nseg) H_PRE(s + 3);
        H_PROC(s);
    }
    // tail
    HW(25); H_PROC(nseg - 2);
    HW(15); H_PROC(nseg - 1);

    mstate[gid] = m;
#undef HW
#undef H_PROC
#undef H_PRE
}

// ---------------- host ----------------

extern "C" void kernel_launch(void* const* d_in, const int* in_sizes, int n_in,
                              void* d_out, int out_size, void* d_ws, size_t ws_size,
                              hipStream_t stream) {
    const float* in_sp = (const float*)d_in[0];
    const float* W0 = (const float*)d_in[1];
    const float* b0 = (const float*)d_in[2];
    const float* W1 = (const float*)d_in[3];
    const float* b1 = (const float*)d_in[4];
    const float* W2 = (const float*)d_in[5];
    const float* b2 = (const float*)d_in[6];
    float* out = (float*)d_out;

    char* p = (char*)d_ws;
    auto carve = [&](size_t bytes) -> void* {
        char* r = p; p += (bytes + 255) & ~(size_t)255; return (void*)r;
    };
    u64*  MASK  = (u64*)carve((size_t)T_STEPS * NB * 8);
    bf16* BT1   = (bf16*)carve((size_t)NH * 2 * NH * 2);
    bf16* BT2   = (bf16*)carve((size_t)128 * 2 * NH * 2);
    float* m0s  = (float*)carve((size_t)NB * NH * 4);
    float* m1s  = (float*)carve((size_t)NB * NH * 4);
    float* m2s  = (float*)carve((size_t)NB * 16 * 4);
    float* I2BUF = (float*)carve((size_t)T_STEPS * NB * 16 * 4);  // full T
    u64*  BITS  = (u64*)carve((size_t)(T_STEPS / SEGO) * 256 * 8);
    size_t fixed = (size_t)(p - (char*)d_ws);

    // Tc | 4000, Tc % 400 == 0, Mc % 256 == 0
    const int tc_opts[3] = {2000, 800, 400};
    int Tc = 400;
    for (int i = 0; i < 3; ++i) {
        size_t Mc_ = (size_t)tc_opts[i] * NB;
        size_t need = fixed
            + ((Mc_ * NH * 4 + 255) & ~(size_t)255)     // IBUF
            + ((Mc_ * NH * 2 + 255) & ~(size_t)255);    // S (bf16)
        if (need <= ws_size) { Tc = tc_opts[i]; break; }
    }
    size_t Mc = (size_t)Tc * NB;
    float* IBUF = (float*)carve(Mc * NH * 4);
    bf16*  S0   = (bf16*)carve(Mc * NH * 2);
    size_t sbytes = (Mc * NH * 2 + 255) & ~(size_t)255;
    int sdbuf = ((size_t)(p - (char*)d_ws) + sbytes <= ws_size) ? 1 : 0;
    bf16* S1 = sdbuf ? (bf16*)carve(Mc * NH * 2) : S0;
    auto Sb = [&](int c) -> bf16* { return (c & 1) ? S1 : S0; };

    // merged prep
    int nM = NB * NH * 2 + NB * 16;
    const int ZB = (nM + 255) / 256;
    const int MB = (T_STEPS * NB) / 4;
    const int L2B = (128 * 2 * NH + 255) / 256;
    k_prep<<<ZB + MB + 256 + L2B, 256, 0, stream>>>(
        in_sp, MASK, W1, BT1, W2, BT2, m0s, nM, ZB, MB);

    const int C = T_STEPS / Tc;
    const int gx8 = (int)(Mc / 256);
    const int gthin = (int)(Mc / 64);

    // chunk 0's layer-0 scan (standalone)
    k_scan_l0<<<256, 64, 0, stream>>>(MASK, W0, b0, m0s, Sb(0), Tc);

    const float beta = (float)exp(-0.25 / 10.0);
    for (int c = 0; c < C; ++c) {
        int t0 = c * Tc;
        int doOut = (c >= 1) ? 1 : 0;
        int nL0   = (sdbuf && c + 1 < C) ? 32 : 0;
        int tp = (c - 1) * Tc;
        k_gemm8<<<gx8 * 4 + doOut + nL0, 512, 0, stream>>>(
            Sb(c), BT1, IBUF, gx8,
            doOut ? I2BUF + (size_t)tp * NB * 16 : nullptr, b2, m2s,
            doOut ? BITS + (size_t)(tp / SEGO) * 256 : nullptr, Tc, doOut,
            nL0 ? MASK + (size_t)(t0 + Tc) * NB : nullptr, W0, b0, m0s,
            nL0 ? Sb(c + 1) : nullptr, nL0);
        k_scan_hidden<<<(NB * NH) / 64, 64, 0, stream>>>(IBUF, b1, m1s, Sb(c), Tc, beta);
        k_gemm_thin<<<gthin, 256, 0, stream>>>(Sb(c), BT2,
                                               I2BUF + (size_t)t0 * NB * 16);
        if (!sdbuf && c + 1 < C)
            k_scan_l0<<<256, 64, 0, stream>>>(MASK + (size_t)(t0 + Tc) * NB,
                                              W0, b0, m0s, Sb(c + 1), Tc);
    }
    // final chunk's output scan, then unpack
    int tl = (C - 1) * Tc;
    k_scan_out<<<1, 256, 0, stream>>>(I2BUF + (size_t)tl * NB * 16, b2, m2s,
                                      BITS + (size_t)(tl / SEGO) * 256, Tc);
    int nOut = T_STEPS * NB * N_OUT;
    k_unpack<<<(nOut + 255) / 256, 256, 0, stream>>>(BITS, out, nOut);
}

// Round 28
// 657.735 us; speedup vs baseline: 1.0276x; 1.0276x over previous
//
#include <hip/hip_runtime.h>
#include <hip/hip_bf16.h>
#include <math.h>

// SNN forward: 64 -> 1024 -> 1024 -> 10, T=4000, B=16, LIF beta=exp(-0.025),
// thr=1, hard reset to 0, Dale clamp W>=0.
// R28: exact revert to R25 (658.1us measured best). scan_hidden families
// (bitmask R19-21, deep-prefetch R26-27) all measured null-or-worse vs the
// simple 2-buffer counted-vmcnt version; closed. Final structure:
// prep (1 launch) -> per chunk { scan_l0 | gemm8 [+ scan_out(c-1) tail
// + scan_l0(c+1) tails if ws allows] -> scan_hidden -> thin GEMM } ->
// scan_out(final) -> unpack. gemm8: 256^2 8-phase, shared-A iteration,
// interleaved-limb BT1, st_16x32 swizzle, setprio, vmcnt(8)/(4).

#define T_STEPS 4000
#define NB 16
#define N_IN 64
#define NH 1024
#define N_OUT 10
#define SEGO 40
#define SEGH 40

typedef __attribute__((ext_vector_type(8))) short bf16x8;
typedef __attribute__((ext_vector_type(4))) float f32x4;
typedef __hip_bfloat16 bf16;
typedef unsigned long long u64;

#define ASG(p) (const __attribute__((address_space(1))) void*)(p)
#define ASL(p) (__attribute__((address_space(3))) void*)(p)

#define BETA_C 0.97530991202833261687f   // float(exp(-0.025))

// ---------------- merged prep kernel ----------------

__global__ __launch_bounds__(256) void k_prep(
    const float* __restrict__ in_sp, u64* __restrict__ mask,
    const float* __restrict__ W1, bf16* __restrict__ BT1,
    const float* __restrict__ W2, bf16* __restrict__ BT2,
    float* __restrict__ mst, int nM, int ZB, int MB) {
    __shared__ float Wlds[64][65];
    int b = blockIdx.x;
    const int tid = threadIdx.x;
    if (b < ZB) {                                  // zero membrane states
        int i = b * 256 + tid;
        if (i < nM) mst[i] = 0.f;
        return;
    }
    b -= ZB;
    if (b < MB) {                                  // input spike masks
        int w = b * 4 + (tid >> 6);
        int lane = tid & 63;
        float v = in_sp[(size_t)w * 64 + lane];
        u64 bal = __ballot(v > 0.5f);
        if (lane == 0) mask[w] = bal;
        return;
    }
    b -= MB;
    if (b < 256) {                                 // limbs_t: BT1 interleaved
        const int lane = tid & 63;
        const int wr   = tid >> 6;
        const int k0 = (b & 15) * 64;
        const int n0 = (b >> 4) * 64;
#pragma unroll
        for (int rr = 0; rr < 16; ++rr) {
            int kl = wr * 16 + rr;
            Wlds[kl][lane] = W1[(size_t)(k0 + kl) * 1024 + n0 + lane];
        }
        __syncthreads();
#pragma unroll
        for (int rr = 0; rr < 16; ++rr) {
            int nl = wr * 16 + rr;
            float w = fmaxf(Wlds[lane][nl], 0.f);  // Dale's law clamp
            bf16 h = __float2bfloat16(w);
            float hf = __bfloat162float(h);
            bf16 l = __float2bfloat16(w - hf);
            size_t base = (size_t)(n0 + nl) * 2048 + 2 * k0 + lane;
            BT1[base] = h;
            BT1[base + 64] = l;
        }
        return;
    }
    b -= 256;
    {                                              // limbs: BT2 [128][2048]
        int idx = b * 256 + tid;
        int total = 128 * 2 * NH;
        if (idx >= total) return;
        int n  = idx / (2 * NH);
        int k2 = idx - n * (2 * NH);
        int lo = (k2 >= NH);
        int k = lo ? (k2 - NH) : k2;
        float v = 0.f;
        if (n < N_OUT) {
            float w = fmaxf(W2[(size_t)k * N_OUT + n], 0.f);
            float hi = __bfloat162float(__float2bfloat16(w));
            v = lo ? (w - hi) : w;
        }
        BT2[idx] = __float2bfloat16(v);
    }
}

// Unpack scan_out bit-spikes.
__global__ void k_unpack(const u64* __restrict__ BITS, float* __restrict__ out,
                         int total) {
    int idx = blockIdx.x * 256 + threadIdx.x;
    if (idx >= total) return;
    int t   = idx / (NB * N_OUT);
    int rem = idx - t * (NB * N_OUT);
    int b = rem / N_OUT;
    int k = rem - b * N_OUT;
    u64 w = BITS[(size_t)(t / SEGO) * 256 + b * 16 + k];
    out[idx] = ((w >> (t % SEGO)) & 1ULL) ? 1.f : 0.f;
}

// ---------------- scan_out body (standalone + gemm8 tail) ----------------

__device__ __forceinline__ void scan_out_body(
    const float* __restrict__ I2, const float* __restrict__ bias,
    float* __restrict__ mstate, u64* __restrict__ BITS,
    int Tc, float* seg, int tid) {
    float* segA = seg;
    float* segB = seg + SEGO * 256;
    const bool act = tid < 256;
    const int lane = tid & 63;
    const int wave = tid >> 6;
    const int k = tid & 15;
    float m = 0.f, bj = 0.f;
    if (act) {
        m = mstate[tid];
        bj = (k < N_OUT) ? bias[k] : 0.f;
    }
    const int nseg = Tc / SEGO;                  // even

#define O_PREFETCH(SEGBUF, SIDX)                                            \
    if (act) {                                                              \
        const float* src = I2 + (size_t)(SIDX) * SEGO * 256                 \
                              + (size_t)wave * 256 + lane * 4;              \
        _Pragma("unroll")                                                   \
        for (int g = 0; g < SEGO / 4; ++g)                                  \
            __builtin_amdgcn_global_load_lds(                               \
                ASG(src + (size_t)(g * 4) * 256),                           \
                ASL(&SEGBUF[(g * 4 + wave) * 256]), 16, 0, 0);              \
    }

#define O_PROC(SEGBUF, SIDX)                                                \
    if (act) {                                                              \
        u64 obits = 0;                                                      \
        _Pragma("unroll")                                                   \
        for (int sb = 0; sb < SEGO / 8; ++sb) {                             \
            float v[8];                                                     \
            _Pragma("unroll")                                               \
            for (int u = 0; u < 8; ++u)                                     \
                v[u] = SEGBUF[(sb * 8 + u) * 256 + tid];                    \
            _Pragma("unroll")                                               \
            for (int u = 0; u < 8; ++u) {                                   \
                m = fmaf(BETA_C, m, v[u] + bj);                             \
                bool sp = (m >= 1.0f);                                      \
                obits |= ((u64)(sp ? 1 : 0)) << (sb * 8 + u);               \
                m = sp ? 0.f : m;                                           \
            }                                                               \
        }                                                                   \
        BITS[(size_t)(SIDX) * 256 + tid] = obits;                           \
    }

    O_PREFETCH(segA, 0);
    O_PREFETCH(segB, 1);
    asm volatile("s_waitcnt vmcnt(10)" ::: "memory");
    __builtin_amdgcn_sched_barrier(0);
    __builtin_amdgcn_s_barrier();
    for (int s = 0; s < nseg; s += 2) {
        O_PROC(segA, s);
        if (s + 2 < nseg) {
            O_PREFETCH(segA, s + 2);
            asm volatile("s_waitcnt vmcnt(11)" ::: "memory");
        } else {
            asm volatile("s_waitcnt vmcnt(1)" ::: "memory");
        }
        __builtin_amdgcn_sched_barrier(0);
        __builtin_amdgcn_s_barrier();
        O_PROC(segB, s + 1);
        if (s + 3 < nseg) {
            O_PREFETCH(segB, s + 3);
            asm volatile("s_waitcnt vmcnt(11)" ::: "memory");
            __builtin_amdgcn_sched_barrier(0);
            __builtin_amdgcn_s_barrier();
        } else if (s + 2 < nseg) {
            asm volatile("s_waitcnt vmcnt(1)" ::: "memory");
            __builtin_amdgcn_sched_barrier(0);
            __builtin_amdgcn_s_barrier();
        }
    }
    if (act) mstate[tid] = m;
#undef O_PREFETCH
#undef O_PROC
}

__global__ __launch_bounds__(256) void k_scan_out(
    const float* __restrict__ I2, const float* __restrict__ bias,
    float* __restrict__ mstate, u64* __restrict__ BITS, int Tc) {
    __shared__ __align__(16) float seg[2 * SEGO * 256];
    scan_out_body(I2, bias, mstate, BITS, Tc, seg, threadIdx.x);
}

// ---------------- scan_l0 body (standalone + gemm8 tail) ----------------

__device__ __forceinline__ void scan_l0_body(
    const u64* __restrict__ mask, const float* __restrict__ W0,
    const float* __restrict__ bias, float* __restrict__ mstate,
    bf16* __restrict__ S, int Tc, int b0, int lane, float* IL) {
    const int b  = b0 >> 4;
    const int q  = b0 & 15;
    const int j0 = q * 64;
    const int gid = b0 * 64 + lane;
    const int r16 = lane & 15;
    const int kg  = lane >> 4;
    bf16x8 bh[4][2], bl[4][2];
#pragma unroll
    for (int jt = 0; jt < 4; ++jt)
#pragma unroll
        for (int kk = 0; kk < 2; ++kk)
#pragma unroll
            for (int e = 0; e < 8; ++e) {
                int k = kk * 32 + kg * 8 + e;
                float w = fmaxf(W0[(size_t)k * 1024 + j0 + jt * 16 + r16], 0.f);
                bf16 h = __float2bfloat16(w);
                float hf = __bfloat162float(h);
                bf16 l = __float2bfloat16(w - hf);
                bh[jt][kk][e] = *(short*)&h;
                bl[jt][kk][e] = *(short*)&l;
            }
    float m = mstate[gid];
    const float bj = bias[j0 + lane];
    const size_t stride = (size_t)NB * NH;
    const int ntile = Tc / 16;
    const int tmax = ntile - 1;

#define LOADM(TT) mask[(size_t)(((TT) <= tmax ? (TT) : tmax) * 16 + r16) * NB + b]

#define L0_COMPUTE(MSK, P)                                                  \
    {                                                                       \
        f32x4 acc[4] = {};                                                  \
        _Pragma("unroll")                                                   \
        for (int kk = 0; kk < 2; ++kk) {                                    \
            unsigned byte8 = (unsigned)(((MSK) >> (kk * 32 + kg * 8)) & 0xFF); \
            bf16x8 af;                                                      \
            _Pragma("unroll")                                               \
            for (int e = 0; e < 8; ++e)                                     \
                af[e] = ((byte8 >> e) & 1) ? (short)0x3F80 : (short)0;      \
            _Pragma("unroll")                                               \
            for (int jt = 0; jt < 4; ++jt) {                                \
                acc[jt] = __builtin_amdgcn_mfma_f32_16x16x32_bf16(          \
                    af, bh[jt][kk], acc[jt], 0, 0, 0);                      \
                acc[jt] = __builtin_amdgcn_mfma_f32_16x16x32_bf16(          \
                    af, bl[jt][kk], acc[jt], 0, 0, 0);                      \
            }                                                               \
        }                                                                   \
        _Pragma("unroll")                                                   \
        for (int jt = 0; jt < 4; ++jt)                                      \
            _Pragma("unroll")                                               \
            for (int rr = 0; rr < 4; ++rr)                                  \
                IL[(P) * 1088 + (kg * 4 + rr) * 68 + jt * 16 + r16] = acc[jt][rr]; \
    }

    u64 mc = LOADM(0);
    L0_COMPUTE(mc, 0);
    u64 mn = LOADM(1);
    for (int tt = 0; tt < ntile; ++tt) {
        __builtin_amdgcn_s_barrier();            // tile tt resident
        float v[16];
#pragma unroll
        for (int u = 0; u < 16; ++u)
            v[u] = IL[(tt & 1) * 1088 + u * 68 + lane];
        u64 m2 = LOADM(tt + 2);
        if (tt + 1 < ntile) L0_COMPUTE(mn, (tt + 1) & 1);
        unsigned short o[16];
#pragma unroll
        for (int u = 0; u < 16; ++u) {
            m = fmaf(BETA_C, m, v[u] + bj);
            bool sp = (m >= 1.0f);
            o[u] = sp ? (unsigned short)0x3F80 : (unsigned short)0;
            m = sp ? 0.f : m;
        }
#pragma unroll
        for (int u = 0; u < 16; ++u)
            ((unsigned short*)S)[(size_t)(tt * 16 + u) * stride + gid] = o[u];
        mn = m2;
    }
    mstate[gid] = m;
#undef L0_COMPUTE
#undef LOADM
}

__global__ __launch_bounds__(64) void k_scan_l0(
    const u64* __restrict__ mask, const float* __restrict__ W0,
    const float* __restrict__ bias, float* __restrict__ mstate,
    bf16* __restrict__ S, int Tc) {
    __shared__ __align__(16) float IL[2 * 16 * 68];
    scan_l0_body(mask, W0, bias, mstate, S, Tc, blockIdx.x, threadIdx.x, IL);
}

// ---------------- thin GEMM v2 (layer 2) ----------------

__global__ __launch_bounds__(256) void k_gemm_thin(
    const bf16* __restrict__ A, const bf16* __restrict__ BT,
    float* __restrict__ C) {
    const int tid  = threadIdx.x;
    const int lane = tid & 63;
    const int wave = tid >> 6;
    const int r16 = lane & 15;
    const int kg  = lane >> 4;
    const int m0 = blockIdx.x * 64 + wave * 16;
    f32x4 acc = {};
    const bf16* ap = A + (size_t)(m0 + r16) * 1024 + kg * 8;
    const bf16* bh = BT + (size_t)r16 * 2048 + kg * 8;
    const bf16* bl = bh + 1024;
#pragma unroll 8
    for (int kt = 0; kt < 32; ++kt) {
        const int ka = kt * 32;
        bf16x8 af  = *(const bf16x8*)(ap + ka);
        bf16x8 bfh = *(const bf16x8*)(bh + ka);
        bf16x8 bfl = *(const bf16x8*)(bl + ka);
        acc = __builtin_amdgcn_mfma_f32_16x16x32_bf16(af, bfh, acc, 0, 0, 0);
        acc = __builtin_amdgcn_mfma_f32_16x16x32_bf16(af, bfl, acc, 0, 0, 0);
    }
#pragma unroll
    for (int rr = 0; rr < 4; ++rr)
        C[(size_t)(m0 + kg * 4 + rr) * 16 + r16] = acc[rr];
}

// ---------------- 256^2 8-phase GEMM (layer 1), shared-A iteration ---------

__global__ __launch_bounds__(512) void k_gemm8(
    const bf16* __restrict__ A, const bf16* __restrict__ BT,
    float* __restrict__ C, int gx,
    const float* __restrict__ I2t, const float* __restrict__ b2t,
    float* __restrict__ m2t, u64* __restrict__ BITSt, int tcT, int doTailOut,
    const u64* __restrict__ maskN, const float* __restrict__ W0N,
    const float* __restrict__ b0N, float* __restrict__ m0N,
    bf16* __restrict__ SN, int nL0blk) {
    __shared__ __align__(16) char LDS[131072];
    const int tid  = threadIdx.x;
    const int lane = tid & 63;
    const int wave = tid >> 6;

    const int nwg = gridDim.x - doTailOut - nL0blk;
    const int wg  = blockIdx.x;
    if (wg >= nwg) {
        int tix = wg - nwg;
        if (tix < doTailOut) {
            scan_out_body(I2t, b2t, m2t, BITSt, tcT, (float*)LDS, tid);
        } else {
            int unit = (tix - doTailOut) * 8 + wave;
            float* IL = (float*)LDS + wave * 2176;
            scan_l0_body(maskN, W0N, b0N, m0N, SN, tcT, unit, lane, IL);
        }
        return;
    }

    const int KA = 1024;
    const int q = nwg >> 3, r = nwg & 7;
    const int xcd = wg & 7, idx0 = wg >> 3;
    const int swz = (xcd < r ? xcd * (q + 1) : r * (q + 1) + (xcd - r) * q) + idx0;
    const int gy = nwg / gx;              // 4
    const int n0 = (swz % gy) * 256;
    const int m0 = (swz / gy) * 256;

    const int wm = (wave >> 2) * 128;
    const int wn = (wave & 3) * 64;
    const int r16l = lane & 15;
    const int kg   = lane >> 4;
    const int hA   = wave >> 2;
    const int hB   = (wave & 3) >> 1;
    const int wn64 = wave & 1;

    const int po = (r16l * 64 + kg * 16) ^ (((r16l >> 3) & 1) << 5);
    const char* bA[2] = { LDS + hA * 16384 + po,
                          LDS + 32768 + hA * 16384 + po };
    const char* bB[2] = { LDS + 65536 + hB * 16384 + po,
                          LDS + 98304 + hB * 16384 + po };
    const int bOff = wn64 * 8192;

    int s_row[2], s_col[2];
#pragma unroll
    for (int rr = 0; rr < 2; ++rr) {
        int d = (rr * 512 + tid) * 16;
        int l = d ^ (((d >> 9) & 1) << 5);
        int sub = l >> 10;
        int w = l & 1023;
        s_row[rr] = (sub >> 1) * 16 + (w >> 6);
        s_col[rr] = ((sub & 1) * 64 + (w & 63)) >> 1;
    }

#define STAGE_A(ADST, HALF, K0)                                             \
    {                                                                       \
        _Pragma("unroll")                                                   \
        for (int rr = 0; rr < 2; ++rr)                                      \
            __builtin_amdgcn_global_load_lds(                               \
                ASG(A + (size_t)(m0 + (HALF) * 128 + s_row[rr]) * KA        \
                    + (K0) + s_col[rr]),                                    \
                ASL(LDS + (ADST) * 32768 + (HALF) * 16384                   \
                    + (rr * 512 + wave * 64) * 16),                         \
                16, 0, 0);                                                  \
    }
#define STAGE_B(BUF, HALF, K0)                                              \
    {                                                                       \
        _Pragma("unroll")                                                   \
        for (int rr = 0; rr < 2; ++rr)                                      \
            __builtin_amdgcn_global_load_lds(                               \
                ASG(BT + (size_t)(n0 + (HALF) * 128 + s_row[rr]) * 2048     \
                    + (K0) + s_col[rr]),                                    \
                ASL(LDS + 65536 + (BUF) * 32768 + (HALF) * 16384            \
                    + (rr * 512 + wave * 64) * 16),                         \
                16, 0, 0);                                                  \
    }

    f32x4 acc[8][4] = {};
    bf16x8 a[4][2], b[4][2];

#define MM(MIB, NIB)                                                        \
    {                                                                       \
        _Pragma("unroll")                                                   \
        for (int i = 0; i < 4; ++i)                                         \
            _Pragma("unroll")                                               \
            for (int j = 0; j < 2; ++j) {                                   \
                acc[(MIB) + i][(NIB) + j] =                                 \
                    __builtin_amdgcn_mfma_f32_16x16x32_bf16(                \
                        a[i][0], b[(NIB) + j][0], acc[(MIB) + i][(NIB) + j], 0, 0, 0); \
                acc[(MIB) + i][(NIB) + j] =                                 \
                    __builtin_amdgcn_mfma_f32_16x16x32_bf16(                \
                        a[i][1], b[(NIB) + j][1], acc[(MIB) + i][(NIB) + j], 0, 0, 0); \
            }                                                               \
    }

#define PH_SYNC()                                                           \
    __builtin_amdgcn_s_barrier();                                           \
    asm volatile("s_waitcnt lgkmcnt(0)" ::: "memory");                      \
    __builtin_amdgcn_sched_barrier(0);

#define KT_EVEN(ABUF, BKN, AKN)                                             \
    {                                                                       \
        _Pragma("unroll")                                                   \
        for (int i = 0; i < 4; ++i) {                                       \
            a[i][0] = *(const bf16x8*)(bA[ABUF] + i * 2048);                \
            a[i][1] = *(const bf16x8*)(bA[ABUF] + i * 2048 + 1024);         \
        }                                                                   \
        _Pragma("unroll")                                                   \
        for (int j = 0; j < 2; ++j) {                                       \
            b[j][0] = *(const bf16x8*)(bB[0] + bOff + j * 2048);            \
            b[j][1] = *(const bf16x8*)(bB[0] + bOff + j * 2048 + 1024);     \
        }                                                                   \
        PH_SYNC();                                                          \
        __builtin_amdgcn_s_setprio(1);                                      \
        MM(0, 0);                                                           \
        __builtin_amdgcn_s_setprio(0);                                      \
        __builtin_amdgcn_s_barrier();                                       \
        _Pragma("unroll")                                                   \
        for (int j = 0; j < 2; ++j) {                                       \
            b[2 + j][0] = *(const bf16x8*)(bB[0] + bOff + (2 + j) * 2048);  \
            b[2 + j][1] = *(const bf16x8*)(bB[0] + bOff + (2 + j) * 2048 + 1024); \
        }                                                                   \
        PH_SYNC();                                                          \
        __builtin_amdgcn_s_setprio(1);                                      \
        MM(0, 2);                                                           \
        __builtin_amdgcn_s_setprio(0);                                      \
        __builtin_amdgcn_s_barrier();                                       \
        _Pragma("unroll")                                                   \
        for (int i = 0; i < 4; ++i) {                                       \
            a[i][0] = *(const bf16x8*)(bA[ABUF] + (4 + i) * 2048);          \
            a[i][1] = *(const bf16x8*)(bA[ABUF] + (4 + i) * 2048 + 1024);   \
        }                                                                   \
        STAGE_B(0, 0, BKN);                                                 \
        STAGE_B(0, 1, BKN);                                                 \
        PH_SYNC();                                                          \
        __builtin_amdgcn_s_setprio(1);                                      \
        MM(4, 0);                                                           \
        __builtin_amdgcn_s_setprio(0);                                      \
        __builtin_amdgcn_s_barrier();                                       \
        STAGE_A((ABUF) ^ 1, 0, AKN);                                        \
        STAGE_A((ABUF) ^ 1, 1, AKN);                                        \
        PH_SYNC();                                                          \
        __builtin_amdgcn_s_setprio(1);                                      \
        MM(4, 2);                                                           \
        __builtin_amdgcn_s_setprio(0);                                      \
        asm volatile("s_waitcnt vmcnt(8)" ::: "memory");                    \
        __builtin_amdgcn_sched_barrier(0);                                  \
        __builtin_amdgcn_s_barrier();                                       \
    }

#define KT_ODD(ABUF, BKN)                                                   \
    {                                                                       \
        _Pragma("unroll")                                                   \
        for (int i = 0; i < 4; ++i) {                                       \
            a[i][0] = *(const bf16x8*)(bA[ABUF] + i * 2048);                \
            a[i][1] = *(const bf16x8*)(bA[ABUF] + i * 2048 + 1024);         \
        }                                                                   \
        _Pragma("unroll")                                                   \
        for (int j = 0; j < 2; ++j) {                                       \
            b[j][0] = *(const bf16x8*)(bB[1] + bOff + j * 2048);            \
            b[j][1] = *(const bf16x8*)(bB[1] + bOff + j * 2048 + 1024);     \
        }                                                                   \
        PH_SYNC();                                                          \
        __builtin_amdgcn_s_setprio(1);                                      \
        MM(0, 0);                                                           \
        __builtin_amdgcn_s_setprio(0);                                      \
        __builtin_amdgcn_s_barrier();                                       \
        _Pragma("unroll")                                                   \
        for (int j = 0; j < 2; ++j) {                                       \
            b[2 + j][0] = *(const bf16x8*)(bB[1] + bOff + (2 + j) * 2048);  \
            b[2 + j][1] = *(const bf16x8*)(bB[1] + bOff + (2 + j) * 2048 + 1024); \
        }                                                                   \
        PH_SYNC();                                                          \
        __builtin_amdgcn_s_setprio(1);                                      \
        MM(0, 2);                                                           \
        __builtin_amdgcn_s_setprio(0);                                      \
        __builtin_amdgcn_s_barrier();                                       \
        _Pragma("unroll")                                                   \
        for (int i = 0; i < 4; ++i) {                                       \
            a[i][0] = *(const bf16x8*)(bA[ABUF] + (4 + i) * 2048);          \
            a[i][1] = *(const bf16x8*)(bA[ABUF] + (4 + i) * 2048 + 1024);   \
        }                                                                   \
        STAGE_B(1, 0, BKN);                                                 \
        STAGE_B(1, 1, BKN);                                                 \
        PH_SYNC();                                                          \
        __builtin_amdgcn_s_setprio(1);                                      \
        MM(4, 0);                                                           \
        __builtin_amdgcn_s_setprio(0);                                      \
        __builtin_amdgcn_s_barrier();                                       \
        PH_SYNC();                                                          \
        __builtin_amdgcn_s_setprio(1);                                      \
        MM(4, 2);                                                           \
        __builtin_amdgcn_s_setprio(0);                                      \
        asm volatile("s_waitcnt vmcnt(4)" ::: "memory");                    \
        __builtin_amdgcn_sched_barrier(0);                                  \
        __builtin_amdgcn_s_barrier();                                       \
    }

    STAGE_B(0, 0, 0);  STAGE_B(0, 1, 0);
    STAGE_A(0, 0, 0);  STAGE_A(0, 1, 0);
    STAGE_B(1, 0, 64); STAGE_B(1, 1, 64);
    asm volatile("s_waitcnt vmcnt(4)" ::: "memory");
    __builtin_amdgcn_sched_barrier(0);
    __builtin_amdgcn_s_barrier();

    for (int it2 = 0; it2 < 16; it2 += 2) {
        const int ak1 = (64 * (it2 + 1)) & 1023;
        const int be1 = (128 * (it2 + 1)) & 2047;
        KT_EVEN(0, be1, ak1);
        KT_ODD(0, be1 + 64);
        const int ak2 = (64 * (it2 + 2)) & 1023;
        const int be2 = (128 * (it2 + 2)) & 2047;
        KT_EVEN(1, be2, ak2);
        KT_ODD(1, be2 + 64);
    }
    asm volatile("s_waitcnt vmcnt(0)" ::: "memory");
    __builtin_amdgcn_sched_barrier(0);

#pragma unroll
    for (int mi = 0; mi < 8; ++mi)
#pragma unroll
        for (int ni = 0; ni < 4; ++ni)
#pragma unroll
            for (int rr = 0; rr < 4; ++rr) {
                int row = m0 + wm + mi * 16 + kg * 4 + rr;
                int col = n0 + wn + ni * 16 + r16l;
                C[(size_t)row * 1024 + col] = acc[mi][ni][rr];
            }
#undef KT_ODD
#undef KT_EVEN
#undef PH_SYNC
#undef MM
#undef STAGE_A
#undef STAGE_B
}

// ---------------- hidden layer 1 scan (R24 version, measured best) --------

__global__ __launch_bounds__(64) void k_scan_hidden(
    const float* __restrict__ I, const float* __restrict__ bias,
    float* __restrict__ mstate, bf16* __restrict__ S, int Tc, float beta) {
    __shared__ __align__(16) float segA[SEGH * 64];
    __shared__ __align__(16) float segB[SEGH * 64];
    const int lane = threadIdx.x;
    const int gid  = blockIdx.x * 64 + lane;
    const int j = gid & (NH - 1);
    float m = mstate[gid];
    const float bj = bias[j];
    const size_t stride = (size_t)NB * NH;
    const int nseg = Tc / SEGH;                  // even
    const int lrow = lane >> 4;
    const int lcol = (lane & 15) << 2;

#define H_PREFETCH(SEGBUF, SIDX)                                            \
    {                                                                       \
        const float* src = I + (size_t)(SIDX) * SEGH * stride               \
                             + (size_t)lrow * stride + blockIdx.x * 64 + lcol; \
        _Pragma("unroll")                                                   \
        for (int g = 0; g < SEGH / 4; ++g)                                  \
            __builtin_amdgcn_global_load_lds(                               \
                ASG(src + (size_t)(g * 4) * stride),                        \
                ASL(&SEGBUF[g * 256]), 16, 0, 0);                           \
    }

#define H_PROC(SEGBUF, SIDX)                                                \
    {                                                                       \
        const int btt = (SIDX) * SEGH;                                      \
        _Pragma("unroll")                                                   \
        for (int sb = 0; sb < SEGH / 8; ++sb) {                             \
            float v[8];                                                     \
            _Pragma("unroll")                                               \
            for (int u = 0; u < 8; ++u)                                     \
                v[u] = SEGBUF[(sb * 8 + u) * 64 + lane];                    \
            unsigned short o[8];                                            \
            _Pragma("unroll")                                               \
            for (int u = 0; u < 8; ++u) {                                   \
                m = fmaf(beta, m, v[u] + bj);                               \
                bool sp = (m >= 1.0f);                                      \
                o[u] = sp ? (unsigned short)0x3F80 : (unsigned short)0;     \
                m = sp ? 0.f : m;                                           \
            }                                                               \
            _Pragma("unroll")                                               \
            for (int u = 0; u < 8; ++u)                                     \
                ((unsigned short*)S)[(size_t)(btt + sb * 8 + u) * stride + gid] = o[u]; \
        }                                                                   \
    }

    H_PREFETCH(segA, 0);
    H_PREFETCH(segB, 1);
    asm volatile("s_waitcnt vmcnt(10)" ::: "memory");
    __builtin_amdgcn_sched_barrier(0);
    for (int s = 0; s < nseg; s += 2) {
        H_PROC(segA, s);
        if (s + 2 < nseg) {
            H_PREFETCH(segA, s + 2);
            asm volatile("s_waitcnt vmcnt(50)" ::: "memory");
        } else {
            asm volatile("s_waitcnt vmcnt(40)" ::: "memory");
        }
        __builtin_amdgcn_sched_barrier(0);
        H_PROC(segB, s + 1);
        if (s + 3 < nseg) {
            H_PREFETCH(segB, s + 3);
            asm volatile("s_waitcnt vmcnt(50)" ::: "memory");
            __builtin_amdgcn_sched_barrier(0);
        } else if (s + 2 < nseg) {
            asm volatile("s_waitcnt vmcnt(40)" ::: "memory");
            __builtin_amdgcn_sched_barrier(0);
        }
    }
    mstate[gid] = m;
#undef H_PREFETCH
#undef H_PROC
}

// ---------------- host ----------------

extern "C" void kernel_launch(void* const* d_in, const int* in_sizes, int n_in,
                              void* d_out, int out_size, void* d_ws, size_t ws_size,
                              hipStream_t stream) {
    const float* in_sp = (const float*)d_in[0];
    const float* W0 = (const float*)d_in[1];
    const float* b0 = (const float*)d_in[2];
    const float* W1 = (const float*)d_in[3];
    const float* b1 = (const float*)d_in[4];
    const float* W2 = (const float*)d_in[5];
    const float* b2 = (const float*)d_in[6];
    float* out = (float*)d_out;

    char* p = (char*)d_ws;
    auto carve = [&](size_t bytes) -> void* {
        char* r = p; p += (bytes + 255) & ~(size_t)255; return (void*)r;
    };
    u64*  MASK  = (u64*)carve((size_t)T_STEPS * NB * 8);
    bf16* BT1   = (bf16*)carve((size_t)NH * 2 * NH * 2);
    bf16* BT2   = (bf16*)carve((size_t)128 * 2 * NH * 2);
    float* m0s  = (float*)carve((size_t)NB * NH * 4);
    float* m1s  = (float*)carve((size_t)NB * NH * 4);
    float* m2s  = (float*)carve((size_t)NB * 16 * 4);
    float* I2BUF = (float*)carve((size_t)T_STEPS * NB * 16 * 4);  // full T
    u64*  BITS  = (u64*)carve((size_t)(T_STEPS / SEGO) * 256 * 8);
    size_t fixed = (size_t)(p - (char*)d_ws);

    // Tc | 4000, Tc % 400 == 0, Mc % 256 == 0
    const int tc_opts[3] = {2000, 800, 400};
    int Tc = 400;
    for (int i = 0; i < 3; ++i) {
        size_t Mc_ = (size_t)tc_opts[i] * NB;
        size_t need = fixed
            + ((Mc_ * NH * 4 + 255) & ~(size_t)255)     // IBUF
            + ((Mc_ * NH * 2 + 255) & ~(size_t)255);    // S (bf16)
        if (need <= ws_size) { Tc = tc_opts[i]; break; }
    }
    size_t Mc = (size_t)Tc * NB;
    float* IBUF = (float*)carve(Mc * NH * 4);
    bf16*  S0   = (bf16*)carve(Mc * NH * 2);
    size_t sbytes = (Mc * NH * 2 + 255) & ~(size_t)255;
    int sdbuf = ((size_t)(p - (char*)d_ws) + sbytes <= ws_size) ? 1 : 0;
    bf16* S1 = sdbuf ? (bf16*)carve(Mc * NH * 2) : S0;
    auto Sb = [&](int c) -> bf16* { return (c & 1) ? S1 : S0; };

    // merged prep
    int nM = NB * NH * 2 + NB * 16;
    const int ZB = (nM + 255) / 256;
    const int MB = (T_STEPS * NB) / 4;
    const int L2B = (128 * 2 * NH + 255) / 256;
    k_prep<<<ZB + MB + 256 + L2B, 256, 0, stream>>>(
        in_sp, MASK, W1, BT1, W2, BT2, m0s, nM, ZB, MB);

    const int C = T_STEPS / Tc;
    const int gx8 = (int)(Mc / 256);
    const int gthin = (int)(Mc / 64);

    // chunk 0's layer-0 scan (standalone)
    k_scan_l0<<<256, 64, 0, stream>>>(MASK, W0, b0, m0s, Sb(0), Tc);

    const float beta = (float)exp(-0.25 / 10.0);
    for (int c = 0; c < C; ++c) {
        int t0 = c * Tc;
        int doOut = (c >= 1) ? 1 : 0;
        int nL0   = (sdbuf && c + 1 < C) ? 32 : 0;
        int tp = (c - 1) * Tc;
        k_gemm8<<<gx8 * 4 + doOut + nL0, 512, 0, stream>>>(
            Sb(c), BT1, IBUF, gx8,
            doOut ? I2BUF + (size_t)tp * NB * 16 : nullptr, b2, m2s,
            doOut ? BITS + (size_t)(tp / SEGO) * 256 : nullptr, Tc, doOut,
            nL0 ? MASK + (size_t)(t0 + Tc) * NB : nullptr, W0, b0, m0s,
            nL0 ? Sb(c + 1) : nullptr, nL0);
        k_scan_hidden<<<(NB * NH) / 64, 64, 0, stream>>>(IBUF, b1, m1s, Sb(c), Tc, beta);
        k_gemm_thin<<<gthin, 256, 0, stream>>>(Sb(c), BT2,
                                               I2BUF + (size_t)t0 * NB * 16);
        if (!sdbuf && c + 1 < C)
            k_scan_l0<<<256, 64, 0, stream>>>(MASK + (size_t)(t0 + Tc) * NB,
                                              W0, b0, m0s, Sb(c + 1), Tc);
    }
    // final chunk's output scan, then unpack
    int tl = (C - 1) * Tc;
    k_scan_out<<<1, 256, 0, stream>>>(I2BUF + (size_t)tl * NB * 16, b2, m2s,
                                      BITS + (size_t)(tl / SEGO) * 256, Tc);
    int nOut = T_STEPS * NB * N_OUT;
    k_unpack<<<(nOut + 255) / 256, 256, 0, stream>>>(BITS, out, nOut);
}